// Round 11
// baseline (492.394 us; speedup 1.0000x reference)
//
#include <hip/hip_runtime.h>
#include <math.h>

#define BB 512
#define TT 512
#define OO 64

typedef float f32x4 __attribute__((ext_vector_type(4)));

// =====================================================================
// Kernel 1: transpose trans (16 KB) into ws so conf-pass rows coalesce
// Tt[g*64+i] = trans[i*64+g] = T[i][g]
// =====================================================================
__global__ void crf_transpose(const float* __restrict__ trans,
                              float* __restrict__ Tt) {
    for (int k = threadIdx.x; k < OO * OO; k += 256)
        Tt[k] = trans[(k & 63) * OO + (k >> 6)];
}

// =====================================================================
// Kernel 2: single-wave Viterbi scan, max-only (no in-loop argmax).
// Broadcast via v_readlane (state is one value per lane -> SGPR
// broadcast, no LDS round-trip, no asm, no DS ops in the loop).
// R4 proved this structure gets clean register allocation (VGPR=132,
// FETCH=16.7MB, no spills); R4's cost was its in-loop argmax (64
// v_cmp/v_cndmask pairs serializing on VCC) -- removed here: M_t is
// streamed to ws and backpointers are recovered exactly by
// ballot-backtrack (fmax is exact selection => bit-equal recompute).
// =====================================================================
__global__ __launch_bounds__(64) void crf_scan(
    const float* __restrict__ logits,   // [B][T][O]
    const float* __restrict__ trans,    // [O][O]
    const int*   __restrict__ seqlens,  // [B]
    float* __restrict__ out_tags,       // [B][T] (f32)
    float* __restrict__ Mst)            // ws: [B][T][O] f32  (M_0 = 0 row)
{
    const int b = blockIdx.x;
    const int j = threadIdx.x;          // tag 0..63 (also "i" in backtrack)

    __shared__ float Tt_lds[OO * OO];   // Tt_lds[g*64+i] = T[i][g]
    __shared__ unsigned char tagl[TT];

    const int L = seqlens[b];
    const float* lg = logits + (size_t)b * TT * OO;
    float* Mw = Mst + (size_t)b * TT * OO;

    // build Tt_lds conflict-free (lane j writes column j of each row)
    {
        const f32x4* rowp = (const f32x4*)(trans + j * OO);
        #pragma unroll
        for (int q = 0; q < 16; ++q) {
            f32x4 rv = rowp[q];
            Tt_lds[(4*q+0) * OO + j] = rv[0];
            Tt_lds[(4*q+1) * OO + j] = rv[1];
            Tt_lds[(4*q+2) * OO + j] = rv[2];
            Tt_lds[(4*q+3) * OO + j] = rv[3];
        }
    }
    // lane j: transition column T[i][j] in registers (coalesced loads)
    float Tc[64];
    #pragma unroll
    for (int r = 0; r < 64; ++r)
        Tc[r] = trans[r * OO + j];

    float s = lg[j];                    // state: one value per lane
    Mw[j] = 0.f;                        // M_0 := 0  (s_0 = x_0 + M_0)

    // 4-deep emission prefetch (uniform-guarded: L, t are wave-uniform)
    float xr1 = (L > 1) ? lg[1 * OO + j] : 0.f;
    float xr2 = (L > 2) ? lg[2 * OO + j] : 0.f;
    float xr3 = (L > 3) ? lg[3 * OO + j] : 0.f;
    float xr4 = (L > 4) ? lg[4 * OO + j] : 0.f;

    const float* lgp = lg + 5 * OO + j;   // -> x_{t+4} at t=1
    float*       mwp = Mw + OO + j;       // -> M_1 slot

    for (int t = 1; t < L; ++t) {
        float x = xr1; xr1 = xr2; xr2 = xr3; xr3 = xr4;
        if (t + 4 < L) xr4 = *lgp;
        lgp += OO;

        const unsigned su = __float_as_uint(s);

        // candidate r = readlane(s, r) + Tc[r]; consumed immediately.
        // 4 independent accumulators; quad form fuses to v_max3.
        #define CAND(r) (__uint_as_float(                                  \
            (unsigned)__builtin_amdgcn_readlane(su, (r))) + Tc[(r)])
        #define QUAD(q) fmaxf(fmaxf(fmaxf(CAND(4*(q)+0), CAND(4*(q)+1)),   \
                                    CAND(4*(q)+2)), CAND(4*(q)+3))
        float m0 = QUAD(0);
        float m1 = QUAD(1);
        float m2 = QUAD(2);
        float m3 = QUAD(3);
        m0 = fmaxf(m0, QUAD(4));
        m1 = fmaxf(m1, QUAD(5));
        m2 = fmaxf(m2, QUAD(6));
        m3 = fmaxf(m3, QUAD(7));
        m0 = fmaxf(m0, QUAD(8));
        m1 = fmaxf(m1, QUAD(9));
        m2 = fmaxf(m2, QUAD(10));
        m3 = fmaxf(m3, QUAD(11));
        m0 = fmaxf(m0, QUAD(12));
        m1 = fmaxf(m1, QUAD(13));
        m2 = fmaxf(m2, QUAD(14));
        m3 = fmaxf(m3, QUAD(15));
        #undef QUAD
        #undef CAND
        float m = fmaxf(fmaxf(m0, m1), fmaxf(m2, m3));

        *mwp = m; mwp += OO;            // stream pre-emission max (off-path)
        s = x + m;                      // loop-carried: pure registers
    }

    // ---- final argmax over lanes (first-max, exact) ----
    float mm = s;
    #pragma unroll
    for (int d = 1; d < 64; d <<= 1)
        mm = fmaxf(mm, __shfl_xor(mm, d));
    unsigned long long bal = __ballot(s == mm);
    int gcur = (int)__builtin_ctzll(bal);

    // ---- fused exact backtrack: first i with d_i == M_t[gcur] ----
    int t = L - 1;
    if (j == 0) tagl[t] = (unsigned char)gcur;

    float Mt = Mw[t * OO + j];                          // M_t row (per-lane)
    float Xp = (t >= 1) ? lg[(t - 1) * OO + j] : 0.f;   // x_{t-1} row
    float Mp = (t >= 1) ? Mw[(t - 1) * OO + j] : 0.f;   // M_{t-1} row
    float Xq = (t >= 2) ? lg[(t - 2) * OO + j] : 0.f;   // prefetch t-2
    float Mq = (t >= 2) ? Mw[(t - 2) * OO + j] : 0.f;

    while (t >= 1) {
        float target = __uint_as_float(
            (unsigned)__builtin_amdgcn_readlane(__float_as_uint(Mt), gcur));
        float d = (Xp + Mp) + Tt_lds[gcur * OO + j];    // bit-exact recompute
        unsigned long long bl = __ballot(d == target);
        gcur = (int)__builtin_ctzll(bl);                // first-max semantics
        if (j == 0) tagl[t - 1] = (unsigned char)gcur;
        Mt = Mp; Xp = Xq; Mp = Mq;
        if (t >= 3) {
            Xq = lg[(t - 3) * OO + j];
            Mq = Mw[(t - 3) * OO + j];
        }
        --t;
    }
    asm volatile("" ::: "memory");      // lane0 tagl writes before wave reads

    float* ot = out_tags + (size_t)b * TT;
    for (int p = j; p < TT; p += 64)
        ot[p] = (p < L) ? (float)tagl[p] : 0.f;
}

// =====================================================================
// Kernel 3: confidences for decoded path only. One wave per (b,p).
// s_p = x_p + M_p (bit-exact reconstruction);
// conf = 1 / sum_i exp(v_i - max v),  v_i = s_p[i] + T[i][tag_{p+1}]
// (v_i = s_p[i] for p == L-1). Exact f32.
// =====================================================================
__global__ __launch_bounds__(256) void crf_conf(
    const float* __restrict__ logits,   // [B][T][O]
    const float* __restrict__ Mst,      // ws: [B][T][O]
    const float* __restrict__ Tt,       // ws: [O][O] transposed
    const float* __restrict__ out_tags, // [B][T]
    const int*   __restrict__ seqlens,  // [B]
    float* __restrict__ out_scores)     // [B][T]
{
    const int b = blockIdx.x >> 7;
    const int p = ((blockIdx.x & 127) << 2) + (threadIdx.x >> 6);
    const int i = threadIdx.x & 63;
    const int L = seqlens[b];

    if (p >= L) {
        if (i == 0) out_scores[(size_t)b * TT + p] = 0.f;
        return;
    }

    const size_t row = ((size_t)b * TT + p) * OO;
    float v = logits[row + i] + Mst[row + i];
    if (p < L - 1) {
        int g = (int)out_tags[(size_t)b * TT + p + 1];
        v += Tt[g * OO + i];
    }

    float m = v;
    #pragma unroll
    for (int d = 1; d < 64; d <<= 1)
        m = fmaxf(m, __shfl_xor(m, d));
    float e = __expf(v - m);
    #pragma unroll
    for (int d = 1; d < 64; d <<= 1)
        e += __shfl_xor(e, d);

    if (i == 0)
        out_scores[(size_t)b * TT + p] = 1.0f / e;
}

// =====================================================================
// Fallback (proven round-1 kernel): used only if ws too small
// =====================================================================
__global__ __launch_bounds__(256) void crf_decode_fallback(
    const float* __restrict__ logits,
    const float* __restrict__ trans,
    const int*   __restrict__ seqlens,
    float* __restrict__ out)
{
    const int b   = blockIdx.x;
    const int tid = threadIdx.x;
    const int j   = tid >> 2;
    const int c   = tid & 3;

    __shared__ unsigned char bpl[TT][OO];
    __shared__ unsigned char scl[TT][OO];
    __shared__ float st2[2][OO];

    const int L = seqlens[b];
    const float* lg = logits + (size_t)b * TT * OO;

    float trc[16];
    #pragma unroll
    for (int i2 = 0; i2 < 16; ++i2)
        trc[i2] = trans[(c * 16 + i2) * OO + j];

    if (tid < OO) st2[0][tid] = lg[tid];
    __syncthreads();

    int cur = 0;
    for (int t = 1; t < L; ++t) {
        float x = lg[t * OO + j];
        float v[16];
        float m = -1e30f;
        int   idx = 0;
        #pragma unroll
        for (int i2 = 0; i2 < 16; ++i2) {
            float val = st2[cur][c * 16 + i2] + trc[i2];
            v[i2] = val;
            if (val > m) { m = val; idx = c * 16 + i2; }
        }
        #pragma unroll
        for (int d = 1; d <= 2; d <<= 1) {
            float mo = __shfl_xor(m, d);
            int   io = __shfl_xor(idx, d);
            if (mo > m || (mo == m && io < idx)) { m = mo; idx = io; }
        }
        float sden = 0.f;
        #pragma unroll
        for (int i2 = 0; i2 < 16; ++i2)
            sden += __expf(v[i2] - m);
        #pragma unroll
        for (int d = 1; d <= 2; d <<= 1)
            sden += __shfl_xor(sden, d);

        if (c == 0) {
            st2[cur ^ 1][j] = x + m;
            bpl[t][j] = (unsigned char)idx;
            float conf = fminf(1.0f / sden, 1.0f);
            scl[t][j] = (unsigned char)(conf * 255.0f + 0.5f);
        }
        cur ^= 1;
        __syncthreads();
    }

    if (tid == 0) {
        float m = -1e30f; int idx = 0;
        for (int jj = 0; jj < OO; ++jj) {
            float vv = st2[cur][jj];
            if (vv > m) { m = vv; idx = jj; }
        }
        float sden = 0.f;
        for (int jj = 0; jj < OO; ++jj)
            sden += __expf(st2[cur][jj] - m);

        float* out_tags   = out + (size_t)b * TT;
        float* out_scores = out + (size_t)BB * TT + (size_t)b * TT;
        out_tags[L - 1]   = (float)idx;
        out_scores[L - 1] = 1.0f / sden;

        int tag = idx;
        for (int t = L - 1; t >= 1; --t) {
            int ntag  = bpl[t][tag];
            float sc  = (float)scl[t][tag] * (1.0f / 255.0f);
            out_tags[t - 1]   = (float)ntag;
            out_scores[t - 1] = sc;
            tag = ntag;
        }
    }

    float* out_tags   = out + (size_t)b * TT;
    float* out_scores = out + (size_t)BB * TT + (size_t)b * TT;
    for (int p = L + tid; p < TT; p += 256) {
        out_tags[p]   = 0.f;
        out_scores[p] = 0.f;
    }
}

extern "C" void kernel_launch(void* const* d_in, const int* in_sizes, int n_in,
                              void* d_out, int out_size, void* d_ws, size_t ws_size,
                              hipStream_t stream) {
    const float* logits = (const float*)d_in[0];
    const float* trans  = (const float*)d_in[1];
    const int*   lens   = (const int*)d_in[2];
    float* out = (float*)d_out;

    const size_t m_bytes  = (size_t)BB * TT * OO * sizeof(float); // 64 MB
    const size_t tt_bytes = (size_t)OO * OO * sizeof(float);      // 16 KB
    if (ws_size >= m_bytes + tt_bytes) {
        float* Mst = (float*)d_ws;
        float* Tt  = (float*)((char*)d_ws + m_bytes);
        float* out_tags   = out;
        float* out_scores = out + (size_t)BB * TT;

        crf_transpose<<<1, 256, 0, stream>>>(trans, Tt);
        crf_scan<<<BB, 64, 0, stream>>>(logits, trans, lens, out_tags, Mst);
        crf_conf<<<BB * 128, 256, 0, stream>>>(logits, Mst, Tt, out_tags, lens,
                                               out_scores);
    } else {
        crf_decode_fallback<<<BB, 256, 0, stream>>>(logits, trans, lens, out);
    }
}

// Round 12
// 464.288 us; speedup vs baseline: 1.0605x; 1.0605x over previous
//
#include <hip/hip_runtime.h>
#include <math.h>

#define BB 512
#define TT 512
#define OO 64

typedef float f32x4 __attribute__((ext_vector_type(4)));

// =====================================================================
// Kernel 1: transpose trans (16 KB) into ws so conf-pass rows coalesce
// Tt[g*64+i] = trans[i*64+g] = T[i][g]
// =====================================================================
__global__ void crf_transpose(const float* __restrict__ trans,
                              float* __restrict__ Tt) {
    for (int k = threadIdx.x; k < OO * OO; k += 256)
        Tt[k] = trans[(k & 63) * OO + (k >> 6)];
}

// =====================================================================
// Kernel 2: single-wave Viterbi scan, max-only, register-resident Tc.
//  - readlane broadcast (VALU-only state exchange; no LDS in loop)
//  - Tc[64] pinned in VGPRs via in-loop keep-alive asm (R11's VGPR=68
//    proved the allocator remats Tc from L1 every step otherwise)
//  - 8-step groups with NAMED double-buffered emission regs: loads for
//    group g+1 issue at group-g top; first consumer is the rotation at
//    group end (~2500 cyc later) -> counted vmcnt, zero exposed latency
//    (the xr1=xr2 shift pipeline consumed loads one step after issue).
//  - M_t streamed to ws; backpointers recovered by ballot-backtrack.
// =====================================================================
__global__ __launch_bounds__(64, 1) void crf_scan(
    const float* __restrict__ logits,   // [B][T][O]
    const float* __restrict__ trans,    // [O][O]
    const int*   __restrict__ seqlens,  // [B]
    float* __restrict__ out_tags,       // [B][T] (f32)
    float* __restrict__ Mst)            // ws: [B][T][O] f32  (M_0 = 0 row)
{
    const int b = blockIdx.x;
    const int j = threadIdx.x;          // tag 0..63 (also "i" in backtrack)

    __shared__ float Tt_lds[OO * OO];   // Tt_lds[g*64+i] = T[i][g]
    __shared__ unsigned char tagl[TT];

    const int L = seqlens[b];
    const float* lg = logits + (size_t)b * TT * OO;
    float* Mw = Mst + (size_t)b * TT * OO;

    // build Tt_lds conflict-free (lane j writes column j of each row)
    {
        const f32x4* rowp = (const f32x4*)(trans + j * OO);
        #pragma unroll
        for (int q = 0; q < 16; ++q) {
            f32x4 rv = rowp[q];
            Tt_lds[(4*q+0) * OO + j] = rv[0];
            Tt_lds[(4*q+1) * OO + j] = rv[1];
            Tt_lds[(4*q+2) * OO + j] = rv[2];
            Tt_lds[(4*q+3) * OO + j] = rv[3];
        }
    }
    // lane j: transition column T[i][j] in registers (coalesced loads)
    float Tc[64];
    #pragma unroll
    for (int r = 0; r < 64; ++r)
        Tc[r] = trans[r * OO + j];

    // pin Tc in VGPRs (prevents remat-by-reload; 4 asms of 16 operands)
    #define KEEPALIVE()                                                    \
      asm volatile("" : "+v"(Tc[0]),"+v"(Tc[1]),"+v"(Tc[2]),"+v"(Tc[3]),   \
                       "+v"(Tc[4]),"+v"(Tc[5]),"+v"(Tc[6]),"+v"(Tc[7]),    \
                       "+v"(Tc[8]),"+v"(Tc[9]),"+v"(Tc[10]),"+v"(Tc[11]),  \
                       "+v"(Tc[12]),"+v"(Tc[13]),"+v"(Tc[14]),"+v"(Tc[15]));\
      asm volatile("" : "+v"(Tc[16]),"+v"(Tc[17]),"+v"(Tc[18]),"+v"(Tc[19]),\
                       "+v"(Tc[20]),"+v"(Tc[21]),"+v"(Tc[22]),"+v"(Tc[23]),\
                       "+v"(Tc[24]),"+v"(Tc[25]),"+v"(Tc[26]),"+v"(Tc[27]),\
                       "+v"(Tc[28]),"+v"(Tc[29]),"+v"(Tc[30]),"+v"(Tc[31]));\
      asm volatile("" : "+v"(Tc[32]),"+v"(Tc[33]),"+v"(Tc[34]),"+v"(Tc[35]),\
                       "+v"(Tc[36]),"+v"(Tc[37]),"+v"(Tc[38]),"+v"(Tc[39]),\
                       "+v"(Tc[40]),"+v"(Tc[41]),"+v"(Tc[42]),"+v"(Tc[43]),\
                       "+v"(Tc[44]),"+v"(Tc[45]),"+v"(Tc[46]),"+v"(Tc[47]));\
      asm volatile("" : "+v"(Tc[48]),"+v"(Tc[49]),"+v"(Tc[50]),"+v"(Tc[51]),\
                       "+v"(Tc[52]),"+v"(Tc[53]),"+v"(Tc[54]),"+v"(Tc[55]),\
                       "+v"(Tc[56]),"+v"(Tc[57]),"+v"(Tc[58]),"+v"(Tc[59]),\
                       "+v"(Tc[60]),"+v"(Tc[61]),"+v"(Tc[62]),"+v"(Tc[63]))
    KEEPALIVE();

    float s = lg[j];                    // state: one value per lane
    Mw[j] = 0.f;                        // M_0 := 0  (s_0 = x_0 + M_0)

    #define CAND(r) (__uint_as_float(                                      \
        (unsigned)__builtin_amdgcn_readlane(su, (r))) + Tc[(r)])
    #define QUAD(q) fmaxf(fmaxf(fmaxf(CAND(4*(q)+0), CAND(4*(q)+1)),       \
                                CAND(4*(q)+2)), CAND(4*(q)+3))
    #define CORE(X, MDST)                                                  \
    {                                                                      \
        const unsigned su = __float_as_uint(s);                            \
        float m0 = QUAD(0);  float m1 = QUAD(1);                           \
        float m2 = QUAD(2);  float m3 = QUAD(3);                           \
        m0 = fmaxf(m0, QUAD(4));   m1 = fmaxf(m1, QUAD(5));                \
        m2 = fmaxf(m2, QUAD(6));   m3 = fmaxf(m3, QUAD(7));                \
        m0 = fmaxf(m0, QUAD(8));   m1 = fmaxf(m1, QUAD(9));                \
        m2 = fmaxf(m2, QUAD(10));  m3 = fmaxf(m3, QUAD(11));               \
        m0 = fmaxf(m0, QUAD(12));  m1 = fmaxf(m1, QUAD(13));               \
        m2 = fmaxf(m2, QUAD(14));  m3 = fmaxf(m3, QUAD(15));               \
        float m = fmaxf(fmaxf(m0, m1), fmaxf(m2, m3));                     \
        MDST = m;                                                          \
        s = (X) + m;                                                       \
    }

    float* mwp = Mw + OO + j;           // -> M_1 slot

    // preload rows 1..8 into named regs (rows always exist: TT=512)
    float xa0, xa1, xa2, xa3, xa4, xa5, xa6, xa7;
    {
        const float* p = lg + OO + j;
        xa0 = p[0*OO]; xa1 = p[1*OO]; xa2 = p[2*OO]; xa3 = p[3*OO];
        xa4 = p[4*OO]; xa5 = p[5*OO]; xa6 = p[6*OO]; xa7 = p[7*OO];
    }

    int t0 = 1;
    for (; t0 + 8 <= L; t0 += 8) {
        // prefetch rows t0+8 .. t0+15 (clamped base when past row 511)
        const float* pf = (t0 + 15 <= TT - 1) ? (lg + (size_t)(t0 + 8) * OO + j)
                                              : (lg + j);
        float nx0 = pf[0*OO]; float nx1 = pf[1*OO];
        float nx2 = pf[2*OO]; float nx3 = pf[3*OO];
        float nx4 = pf[4*OO]; float nx5 = pf[5*OO];
        float nx6 = pf[6*OO]; float nx7 = pf[7*OO];
        __builtin_amdgcn_sched_barrier(0);   // pin loads at group top

        CORE(xa0, mwp[0*OO]) CORE(xa1, mwp[1*OO])
        CORE(xa2, mwp[2*OO]) CORE(xa3, mwp[3*OO])
        CORE(xa4, mwp[4*OO]) CORE(xa5, mwp[5*OO])
        CORE(xa6, mwp[6*OO]) CORE(xa7, mwp[7*OO])
        mwp += 8 * OO;

        // rotate buffers (first consumption of nx*, ~8 steps after issue)
        xa0 = nx0; xa1 = nx1; xa2 = nx2; xa3 = nx3;
        xa4 = nx4; xa5 = nx5; xa6 = nx6; xa7 = nx7;
        KEEPALIVE();
    }
    // tail: < 8 remaining steps
    for (int t = t0; t < L; ++t) {
        float x = lg[(size_t)t * OO + j];
        CORE(x, mwp[0])
        mwp += OO;
    }
    #undef CORE
    #undef QUAD
    #undef CAND
    #undef KEEPALIVE

    // ---- final argmax over lanes (first-max, exact) ----
    float mm = s;
    #pragma unroll
    for (int d = 1; d < 64; d <<= 1)
        mm = fmaxf(mm, __shfl_xor(mm, d));
    unsigned long long bal = __ballot(s == mm);
    int gcur = (int)__builtin_ctzll(bal);

    // ---- fused exact backtrack: first i with d_i == M_t[gcur] ----
    int t = L - 1;
    if (j == 0) tagl[t] = (unsigned char)gcur;

    float Mt = Mw[t * OO + j];                          // M_t row (per-lane)
    float Xp = (t >= 1) ? lg[(t - 1) * OO + j] : 0.f;   // x_{t-1} row
    float Mp = (t >= 1) ? Mw[(t - 1) * OO + j] : 0.f;   // M_{t-1} row
    float Xq = (t >= 2) ? lg[(t - 2) * OO + j] : 0.f;   // prefetch t-2
    float Mq = (t >= 2) ? Mw[(t - 2) * OO + j] : 0.f;

    while (t >= 1) {
        float target = __uint_as_float(
            (unsigned)__builtin_amdgcn_readlane(__float_as_uint(Mt), gcur));
        float d = (Xp + Mp) + Tt_lds[gcur * OO + j];    // bit-exact recompute
        unsigned long long bl = __ballot(d == target);
        gcur = (int)__builtin_ctzll(bl);                // first-max semantics
        if (j == 0) tagl[t - 1] = (unsigned char)gcur;
        Mt = Mp; Xp = Xq; Mp = Mq;
        if (t >= 3) {
            Xq = lg[(t - 3) * OO + j];
            Mq = Mw[(t - 3) * OO + j];
        }
        --t;
    }
    asm volatile("" ::: "memory");      // lane0 tagl writes before wave reads

    float* ot = out_tags + (size_t)b * TT;
    for (int p = j; p < TT; p += 64)
        ot[p] = (p < L) ? (float)tagl[p] : 0.f;
}

// =====================================================================
// Kernel 3: confidences for decoded path only. One wave per (b,p).
// s_p = x_p + M_p (bit-exact reconstruction);
// conf = 1 / sum_i exp(v_i - max v),  v_i = s_p[i] + T[i][tag_{p+1}]
// (v_i = s_p[i] for p == L-1). Exact f32.
// =====================================================================
__global__ __launch_bounds__(256) void crf_conf(
    const float* __restrict__ logits,   // [B][T][O]
    const float* __restrict__ Mst,      // ws: [B][T][O]
    const float* __restrict__ Tt,       // ws: [O][O] transposed
    const float* __restrict__ out_tags, // [B][T]
    const int*   __restrict__ seqlens,  // [B]
    float* __restrict__ out_scores)     // [B][T]
{
    const int b = blockIdx.x >> 7;
    const int p = ((blockIdx.x & 127) << 2) + (threadIdx.x >> 6);
    const int i = threadIdx.x & 63;
    const int L = seqlens[b];

    if (p >= L) {
        if (i == 0) out_scores[(size_t)b * TT + p] = 0.f;
        return;
    }

    const size_t row = ((size_t)b * TT + p) * OO;
    float v = logits[row + i] + Mst[row + i];
    if (p < L - 1) {
        int g = (int)out_tags[(size_t)b * TT + p + 1];
        v += Tt[g * OO + i];
    }

    float m = v;
    #pragma unroll
    for (int d = 1; d < 64; d <<= 1)
        m = fmaxf(m, __shfl_xor(m, d));
    float e = __expf(v - m);
    #pragma unroll
    for (int d = 1; d < 64; d <<= 1)
        e += __shfl_xor(e, d);

    if (i == 0)
        out_scores[(size_t)b * TT + p] = 1.0f / e;
}

// =====================================================================
// Fallback (proven round-1 kernel): used only if ws too small
// =====================================================================
__global__ __launch_bounds__(256) void crf_decode_fallback(
    const float* __restrict__ logits,
    const float* __restrict__ trans,
    const int*   __restrict__ seqlens,
    float* __restrict__ out)
{
    const int b   = blockIdx.x;
    const int tid = threadIdx.x;
    const int j   = tid >> 2;
    const int c   = tid & 3;

    __shared__ unsigned char bpl[TT][OO];
    __shared__ unsigned char scl[TT][OO];
    __shared__ float st2[2][OO];

    const int L = seqlens[b];
    const float* lg = logits + (size_t)b * TT * OO;

    float trc[16];
    #pragma unroll
    for (int i2 = 0; i2 < 16; ++i2)
        trc[i2] = trans[(c * 16 + i2) * OO + j];

    if (tid < OO) st2[0][tid] = lg[tid];
    __syncthreads();

    int cur = 0;
    for (int t = 1; t < L; ++t) {
        float x = lg[t * OO + j];
        float v[16];
        float m = -1e30f;
        int   idx = 0;
        #pragma unroll
        for (int i2 = 0; i2 < 16; ++i2) {
            float val = st2[cur][c * 16 + i2] + trc[i2];
            v[i2] = val;
            if (val > m) { m = val; idx = c * 16 + i2; }
        }
        #pragma unroll
        for (int d = 1; d <= 2; d <<= 1) {
            float mo = __shfl_xor(m, d);
            int   io = __shfl_xor(idx, d);
            if (mo > m || (mo == m && io < idx)) { m = mo; idx = io; }
        }
        float sden = 0.f;
        #pragma unroll
        for (int i2 = 0; i2 < 16; ++i2)
            sden += __expf(v[i2] - m);
        #pragma unroll
        for (int d = 1; d <= 2; d <<= 1)
            sden += __shfl_xor(sden, d);

        if (c == 0) {
            st2[cur ^ 1][j] = x + m;
            bpl[t][j] = (unsigned char)idx;
            float conf = fminf(1.0f / sden, 1.0f);
            scl[t][j] = (unsigned char)(conf * 255.0f + 0.5f);
        }
        cur ^= 1;
        __syncthreads();
    }

    if (tid == 0) {
        float m = -1e30f; int idx = 0;
        for (int jj = 0; jj < OO; ++jj) {
            float vv = st2[cur][jj];
            if (vv > m) { m = vv; idx = jj; }
        }
        float sden = 0.f;
        for (int jj = 0; jj < OO; ++jj)
            sden += __expf(st2[cur][jj] - m);

        float* out_tags   = out + (size_t)b * TT;
        float* out_scores = out + (size_t)BB * TT + (size_t)b * TT;
        out_tags[L - 1]   = (float)idx;
        out_scores[L - 1] = 1.0f / sden;

        int tag = idx;
        for (int t = L - 1; t >= 1; --t) {
            int ntag  = bpl[t][tag];
            float sc  = (float)scl[t][tag] * (1.0f / 255.0f);
            out_tags[t - 1]   = (float)ntag;
            out_scores[t - 1] = sc;
            tag = ntag;
        }
    }

    float* out_tags   = out + (size_t)b * TT;
    float* out_scores = out + (size_t)BB * TT + (size_t)b * TT;
    for (int p = L + tid; p < TT; p += 256) {
        out_tags[p]   = 0.f;
        out_scores[p] = 0.f;
    }
}

extern "C" void kernel_launch(void* const* d_in, const int* in_sizes, int n_in,
                              void* d_out, int out_size, void* d_ws, size_t ws_size,
                              hipStream_t stream) {
    const float* logits = (const float*)d_in[0];
    const float* trans  = (const float*)d_in[1];
    const int*   lens   = (const int*)d_in[2];
    float* out = (float*)d_out;

    const size_t m_bytes  = (size_t)BB * TT * OO * sizeof(float); // 64 MB
    const size_t tt_bytes = (size_t)OO * OO * sizeof(float);      // 16 KB
    if (ws_size >= m_bytes + tt_bytes) {
        float* Mst = (float*)d_ws;
        float* Tt  = (float*)((char*)d_ws + m_bytes);
        float* out_tags   = out;
        float* out_scores = out + (size_t)BB * TT;

        crf_transpose<<<1, 256, 0, stream>>>(trans, Tt);
        crf_scan<<<BB, 64, 0, stream>>>(logits, trans, lens, out_tags, Mst);
        crf_conf<<<BB * 128, 256, 0, stream>>>(logits, Mst, Tt, out_tags, lens,
                                               out_scores);
    } else {
        crf_decode_fallback<<<BB, 256, 0, stream>>>(logits, trans, lens, out);
    }
}

// Round 15
// 386.426 us; speedup vs baseline: 1.2742x; 1.2015x over previous
//
#include <hip/hip_runtime.h>
#include <math.h>

#define BB 512
#define TT 512
#define OO 64

typedef float f32x4 __attribute__((ext_vector_type(4)));

// =====================================================================
// Kernel 1: transpose trans (16 KB) into ws so conf-pass rows coalesce
// =====================================================================
__global__ void crf_transpose(const float* __restrict__ trans,
                              float* __restrict__ Tt) {
    for (int k = threadIdx.x; k < OO * OO; k += 256)
        Tt[k] = trans[(k & 63) * OO + (k >> 6)];
}

// async 8-row (2 KB) emission stage: 2 x global_load_lds dwordx4
// lane j sources 16B at gsrc_lane (= row_base + j*4 floats); HW writes
// LDS at (uniform dst) + lane*16.
__device__ __forceinline__ void stage8(const float* gsrc_lane, float* ldst) {
    __builtin_amdgcn_global_load_lds(
        (const __attribute__((address_space(1))) unsigned int*)(gsrc_lane),
        (__attribute__((address_space(3))) unsigned int*)(ldst), 16, 0, 0);
    __builtin_amdgcn_global_load_lds(
        (const __attribute__((address_space(1))) unsigned int*)(gsrc_lane + 256),
        (__attribute__((address_space(3))) unsigned int*)(ldst + 256), 16, 0, 0);
}

// =====================================================================
// Kernel 2: single-wave Viterbi scan. Invariants (from R8/R14 bugs):
//  (a) no register ever holds an in-flight VMEM load result that could
//      be copied: x reaches registers only via ds_read_b32 inside the
//      per-step DS batch, covered by lgkmcnt(0);
//  (b) ALL in-loop VMEM is inline asm with statically-derived counted
//      waits: per step 1 asm M-store; per 8-step chunk 2 global_load_lds
//      staging ops + one s_waitcnt vmcnt(9) at the boundary
//      (9 = stores newer than the stage pair that must have landed);
//  (c) Tc[64] loaded by 4 asm blocks with vmcnt(0) INSIDE the block ->
//      values complete before any other code runs; asm outputs are not
//      rematerializable -> Tc stays in VGPRs (no compiler reloads that
//      would corrupt the vmcnt count).
// Fixed 511-step schedule; state frozen past L (select). M_t streamed
// to ws; backpointers recovered by exact ballot-backtrack (R10 logic).
// =====================================================================
__global__ __launch_bounds__(64, 1) void crf_scan(
    const float* __restrict__ logits,   // [B][T][O]
    const float* __restrict__ trans,    // [O][O]
    const int*   __restrict__ seqlens,  // [B]
    float* __restrict__ out_tags,       // [B][T] (f32)
    float* __restrict__ Mst)            // ws: [B][T][O] f32  (M_0 = 0 row)
{
    const int b = blockIdx.x;
    const int j = threadIdx.x;          // tag 0..63 (also "i" in backtrack)

    __shared__ __align__(16) float st[OO];
    __shared__ __align__(16) float xl[16][OO];   // 2 chunks x 8 rows
    __shared__ float Tt_lds[OO * OO];   // Tt_lds[g*64+i] = T[i][g]
    __shared__ unsigned char tagl[TT];

    const int L = seqlens[b];
    const float* lg = logits + (size_t)b * TT * OO;
    float* Mw = Mst + (size_t)b * TT * OO;

    // build Tt_lds conflict-free (lane j writes column j of each row)
    {
        const f32x4* rowp = (const f32x4*)(trans + j * OO);
        #pragma unroll
        for (int q = 0; q < 16; ++q) {
            f32x4 rv = rowp[q];
            Tt_lds[(4*q+0) * OO + j] = rv[0];
            Tt_lds[(4*q+1) * OO + j] = rv[1];
            Tt_lds[(4*q+2) * OO + j] = rv[2];
            Tt_lds[(4*q+3) * OO + j] = rv[3];
        }
    }

    // Tc[r] = T[r][j], loaded+drained inside single asm blocks
    float Tc[64];
    #define TCBLK(K)                                                      \
    {                                                                     \
        const float* bp = trans + (K) * 16 * OO + j;                      \
        asm volatile(                                                     \
            "global_load_dword %0, %16, off offset:0\n\t"                 \
            "global_load_dword %1, %16, off offset:256\n\t"               \
            "global_load_dword %2, %16, off offset:512\n\t"               \
            "global_load_dword %3, %16, off offset:768\n\t"               \
            "global_load_dword %4, %16, off offset:1024\n\t"              \
            "global_load_dword %5, %16, off offset:1280\n\t"              \
            "global_load_dword %6, %16, off offset:1536\n\t"              \
            "global_load_dword %7, %16, off offset:1792\n\t"              \
            "global_load_dword %8, %16, off offset:2048\n\t"              \
            "global_load_dword %9, %16, off offset:2304\n\t"              \
            "global_load_dword %10, %16, off offset:2560\n\t"             \
            "global_load_dword %11, %16, off offset:2816\n\t"             \
            "global_load_dword %12, %16, off offset:3072\n\t"             \
            "global_load_dword %13, %16, off offset:3328\n\t"             \
            "global_load_dword %14, %16, off offset:3584\n\t"             \
            "global_load_dword %15, %16, off offset:3840\n\t"             \
            "s_waitcnt vmcnt(0)"                                          \
            : "=&v"(Tc[(K)*16+0]),  "=&v"(Tc[(K)*16+1]),                  \
              "=&v"(Tc[(K)*16+2]),  "=&v"(Tc[(K)*16+3]),                  \
              "=&v"(Tc[(K)*16+4]),  "=&v"(Tc[(K)*16+5]),                  \
              "=&v"(Tc[(K)*16+6]),  "=&v"(Tc[(K)*16+7]),                  \
              "=&v"(Tc[(K)*16+8]),  "=&v"(Tc[(K)*16+9]),                  \
              "=&v"(Tc[(K)*16+10]), "=&v"(Tc[(K)*16+11]),                 \
              "=&v"(Tc[(K)*16+12]), "=&v"(Tc[(K)*16+13]),                 \
              "=&v"(Tc[(K)*16+14]), "=&v"(Tc[(K)*16+15])                  \
            : "v"(bp));                                                   \
    }
    TCBLK(0) TCBLK(1) TCBLK(2) TCBLK(3)
    #undef TCBLK

    const unsigned stbase = (unsigned)(size_t)&st[0];
    const unsigned wrAddr = stbase + (unsigned)(j * 4);
    const unsigned xbase4 = (unsigned)(size_t)&xl[0][0] + (unsigned)(j * 4);

    float s = lg[j];                    // state: one value per lane
    Mw[j] = 0.f;                        // M_0 := 0  (s_0 = x_0 + M_0)

    // stage chunks 0,1 (rows 0-15), drain everything
    stage8(lg + j * 4, &xl[0][0]);
    stage8(lg + 8 * OO + j * 4, &xl[8][0]);
    asm volatile("s_waitcnt vmcnt(0)" ::: "memory");
    __builtin_amdgcn_sched_barrier(0);

    f32x4 r0,r1,r2,r3,r4,r5,r6,r7,r8,r9,r10,r11,r12,r13,r14,r15;
    float xreg;

    // publish s, re-broadcast state, read next emission from LDS.
    // Same-wave DS is in-order: write-then-read race-free.
    #define DSBATCH(XADDR)                                                \
        asm volatile(                                                     \
            "ds_write_b32 %18, %19\n\t"                                   \
            "ds_read_b128 %0, %17 offset:0\n\t"                           \
            "ds_read_b128 %1, %17 offset:16\n\t"                          \
            "ds_read_b128 %2, %17 offset:32\n\t"                          \
            "ds_read_b128 %3, %17 offset:48\n\t"                          \
            "ds_read_b128 %4, %17 offset:64\n\t"                          \
            "ds_read_b128 %5, %17 offset:80\n\t"                          \
            "ds_read_b128 %6, %17 offset:96\n\t"                          \
            "ds_read_b128 %7, %17 offset:112\n\t"                         \
            "ds_read_b128 %8, %17 offset:128\n\t"                         \
            "ds_read_b128 %9, %17 offset:144\n\t"                         \
            "ds_read_b128 %10, %17 offset:160\n\t"                        \
            "ds_read_b128 %11, %17 offset:176\n\t"                        \
            "ds_read_b128 %12, %17 offset:192\n\t"                        \
            "ds_read_b128 %13, %17 offset:208\n\t"                        \
            "ds_read_b128 %14, %17 offset:224\n\t"                        \
            "ds_read_b128 %15, %17 offset:240\n\t"                        \
            "ds_read_b32 %16, %20\n\t"                                    \
            : "=&v"(r0), "=&v"(r1), "=&v"(r2), "=&v"(r3),                 \
              "=&v"(r4), "=&v"(r5), "=&v"(r6), "=&v"(r7),                 \
              "=&v"(r8), "=&v"(r9), "=&v"(r10), "=&v"(r11),               \
              "=&v"(r12), "=&v"(r13), "=&v"(r14), "=&v"(r15), "=&v"(xreg) \
            : "v"(stbase), "v"(wrAddr), "v"(s), "v"(XADDR))

    #define QUAD(q, rr, acc, first)                                       \
    {                                                                     \
        float c0 = rr[0] + Tc[4*(q)+0];                                   \
        float c1 = rr[1] + Tc[4*(q)+1];                                   \
        float c2 = rr[2] + Tc[4*(q)+2];                                   \
        float c3 = rr[3] + Tc[4*(q)+3];                                   \
        float mq = fmaxf(fmaxf(fmaxf(c0, c1), c2), c3);                   \
        acc = first ? mq : fmaxf(acc, mq);                                \
    }

    // prologue: write s_0, read state + x_1 (row 1 -> byte 256)
    DSBATCH(xbase4 + 256u);

    float* mwp = Mw + OO + j;                 // -> M_1 slot
    const float* stgp = lg + 16 * OO + j * 4; // chunk-2 source

    for (int t = 1; t < TT; ++t) {
        asm volatile("s_waitcnt lgkmcnt(0)");  // batch of step t done
        __builtin_amdgcn_sched_barrier(0);
        float x = xreg;

        float m0, m1, m2, m3;
        QUAD(0,  r0,  m0, 1) QUAD(1,  r1,  m1, 1)
        QUAD(2,  r2,  m2, 1) QUAD(3,  r3,  m3, 1)
        QUAD(4,  r4,  m0, 0) QUAD(5,  r5,  m1, 0)
        QUAD(6,  r6,  m2, 0) QUAD(7,  r7,  m3, 0)
        QUAD(8,  r8,  m0, 0) QUAD(9,  r9,  m1, 0)
        QUAD(10, r10, m2, 0) QUAD(11, r11, m3, 0)
        QUAD(12, r12, m0, 0) QUAD(13, r13, m1, 0)
        QUAD(14, r14, m2, 0) QUAD(15, r15, m3, 0)
        float m = fmaxf(fmaxf(m0, m1), fmaxf(m2, m3));

        if ((t & 7) == 7) {                   // uniform chunk boundary
            int c = (t >> 3) + 2;             // chunk to stage
            if (c < 64) {
                __builtin_amdgcn_sched_barrier(0);
                stage8(stgp, &xl[(c & 1) * 8][0]);
                __builtin_amdgcn_sched_barrier(0);
                stgp += 8 * OO;
            }
        }

        asm volatile("global_store_dword %0, %1, off" :: "v"(mwp), "v"(m));
        mwp += OO;
        s = (t < L) ? (x + m) : s;            // frozen past L

        if ((t & 7) == 7) {
            // oldest needed stage pair has >=9 newer stores -> counted
            asm volatile("s_waitcnt vmcnt(9)" ::: "memory");
            __builtin_amdgcn_sched_barrier(0);
        }
        unsigned xaddr = xbase4 + (((unsigned)((t + 1) & 15)) << 8);
        DSBATCH(xaddr);                        // for step t+1 (t=511: unused)
    }
    #undef QUAD
    #undef DSBATCH

    // drain all asm VMEM (backtrack re-reads Mw) + dangling DS batch
    asm volatile("s_waitcnt vmcnt(0) lgkmcnt(0)" ::: "memory");
    __builtin_amdgcn_sched_barrier(0);

    // ---- final argmax over lanes (first-max, exact) ----
    float mm = s;
    #pragma unroll
    for (int d = 1; d < 64; d <<= 1)
        mm = fmaxf(mm, __shfl_xor(mm, d));
    unsigned long long bal = __ballot(s == mm);
    int gcur = (int)__builtin_ctzll(bal);

    // ---- fused exact backtrack: first i with d_i == M_t[gcur] ----
    int t = L - 1;
    if (j == 0) tagl[t] = (unsigned char)gcur;

    float Mt = Mw[t * OO + j];
    float Xp = (t >= 1) ? lg[(t - 1) * OO + j] : 0.f;
    float Mp = (t >= 1) ? Mw[(t - 1) * OO + j] : 0.f;
    float Xq = (t >= 2) ? lg[(t - 2) * OO + j] : 0.f;
    float Mq = (t >= 2) ? Mw[(t - 2) * OO + j] : 0.f;

    while (t >= 1) {
        float target = __uint_as_float(
            (unsigned)__builtin_amdgcn_readlane(__float_as_uint(Mt), gcur));
        float d = (Xp + Mp) + Tt_lds[gcur * OO + j];   // bit-exact recompute
        unsigned long long bl = __ballot(d == target);
        gcur = (int)__builtin_ctzll(bl);               // first-max semantics
        if (j == 0) tagl[t - 1] = (unsigned char)gcur;
        Mt = Mp; Xp = Xq; Mp = Mq;
        if (t >= 3) {
            Xq = lg[(t - 3) * OO + j];
            Mq = Mw[(t - 3) * OO + j];
        }
        --t;
    }
    asm volatile("" ::: "memory");      // lane0 tagl writes before wave reads

    float* ot = out_tags + (size_t)b * TT;
    for (int p = j; p < TT; p += 64)
        ot[p] = (p < L) ? (float)tagl[p] : 0.f;
}

// =====================================================================
// Kernel 3: confidences for decoded path only. One wave per (b,p).
// conf = 1 / sum_i exp(v_i - max v), v_i = (x_p+M_p)[i] + T[i][tag_{p+1}]
// (v_i = s_p[i] for p == L-1). Exact f32. (unchanged, passing)
// =====================================================================
__global__ __launch_bounds__(256) void crf_conf(
    const float* __restrict__ logits,
    const float* __restrict__ Mst,
    const float* __restrict__ Tt,
    const float* __restrict__ out_tags,
    const int*   __restrict__ seqlens,
    float* __restrict__ out_scores)
{
    const int b = blockIdx.x >> 7;
    const int p = ((blockIdx.x & 127) << 2) + (threadIdx.x >> 6);
    const int i = threadIdx.x & 63;
    const int L = seqlens[b];

    if (p >= L) {
        if (i == 0) out_scores[(size_t)b * TT + p] = 0.f;
        return;
    }

    const size_t row = ((size_t)b * TT + p) * OO;
    float v = logits[row + i] + Mst[row + i];
    if (p < L - 1) {
        int g = (int)out_tags[(size_t)b * TT + p + 1];
        v += Tt[g * OO + i];
    }

    float m = v;
    #pragma unroll
    for (int d = 1; d < 64; d <<= 1)
        m = fmaxf(m, __shfl_xor(m, d));
    float e = __expf(v - m);
    #pragma unroll
    for (int d = 1; d < 64; d <<= 1)
        e += __shfl_xor(e, d);

    if (i == 0)
        out_scores[(size_t)b * TT + p] = 1.0f / e;
}

// =====================================================================
// Fallback (proven round-1 kernel): used only if ws too small
// =====================================================================
__global__ __launch_bounds__(256) void crf_decode_fallback(
    const float* __restrict__ logits,
    const float* __restrict__ trans,
    const int*   __restrict__ seqlens,
    float* __restrict__ out)
{
    const int b   = blockIdx.x;
    const int tid = threadIdx.x;
    const int j   = tid >> 2;
    const int c   = tid & 3;

    __shared__ unsigned char bpl[TT][OO];
    __shared__ unsigned char scl[TT][OO];
    __shared__ float st2[2][OO];

    const int L = seqlens[b];
    const float* lg = logits + (size_t)b * TT * OO;

    float trc[16];
    #pragma unroll
    for (int i2 = 0; i2 < 16; ++i2)
        trc[i2] = trans[(c * 16 + i2) * OO + j];

    if (tid < OO) st2[0][tid] = lg[tid];
    __syncthreads();

    int cur = 0;
    for (int t = 1; t < L; ++t) {
        float x = lg[t * OO + j];
        float v[16];
        float m = -1e30f;
        int   idx = 0;
        #pragma unroll
        for (int i2 = 0; i2 < 16; ++i2) {
            float val = st2[cur][c * 16 + i2] + trc[i2];
            v[i2] = val;
            if (val > m) { m = val; idx = c * 16 + i2; }
        }
        #pragma unroll
        for (int d = 1; d <= 2; d <<= 1) {
            float mo = __shfl_xor(m, d);
            int   io = __shfl_xor(idx, d);
            if (mo > m || (mo == m && io < idx)) { m = mo; idx = io; }
        }
        float sden = 0.f;
        #pragma unroll
        for (int i2 = 0; i2 < 16; ++i2)
            sden += __expf(v[i2] - m);
        #pragma unroll
        for (int d = 1; d <= 2; d <<= 1)
            sden += __shfl_xor(sden, d);

        if (c == 0) {
            st2[cur ^ 1][j] = x + m;
            bpl[t][j] = (unsigned char)idx;
            float conf = fminf(1.0f / sden, 1.0f);
            scl[t][j] = (unsigned char)(conf * 255.0f + 0.5f);
        }
        cur ^= 1;
        __syncthreads();
    }

    if (tid == 0) {
        float m = -1e30f; int idx = 0;
        for (int jj = 0; jj < OO; ++jj) {
            float vv = st2[cur][jj];
            if (vv > m) { m = vv; idx = jj; }
        }
        float sden = 0.f;
        for (int jj = 0; jj < OO; ++jj)
            sden += __expf(st2[cur][jj] - m);

        float* out_tags   = out + (size_t)b * TT;
        float* out_scores = out + (size_t)BB * TT + (size_t)b * TT;
        out_tags[L - 1]   = (float)idx;
        out_scores[L - 1] = 1.0f / sden;

        int tag = idx;
        for (int t = L - 1; t >= 1; --t) {
            int ntag  = bpl[t][tag];
            float sc  = (float)scl[t][tag] * (1.0f / 255.0f);
            out_tags[t - 1]   = (float)ntag;
            out_scores[t - 1] = sc;
            tag = ntag;
        }
    }

    float* out_tags   = out + (size_t)b * TT;
    float* out_scores = out + (size_t)BB * TT + (size_t)b * TT;
    for (int p = L + tid; p < TT; p += 256) {
        out_tags[p]   = 0.f;
        out_scores[p] = 0.f;
    }
}

extern "C" void kernel_launch(void* const* d_in, const int* in_sizes, int n_in,
                              void* d_out, int out_size, void* d_ws, size_t ws_size,
                              hipStream_t stream) {
    const float* logits = (const float*)d_in[0];
    const float* trans  = (const float*)d_in[1];
    const int*   lens   = (const int*)d_in[2];
    float* out = (float*)d_out;

    const size_t m_bytes  = (size_t)BB * TT * OO * sizeof(float); // 64 MB
    const size_t tt_bytes = (size_t)OO * OO * sizeof(float);      // 16 KB
    if (ws_size >= m_bytes + tt_bytes) {
        float* Mst = (float*)d_ws;
        float* Tt  = (float*)((char*)d_ws + m_bytes);
        float* out_tags   = out;
        float* out_scores = out + (size_t)BB * TT;

        crf_transpose<<<1, 256, 0, stream>>>(trans, Tt);
        crf_scan<<<BB, 64, 0, stream>>>(logits, trans, lens, out_tags, Mst);
        crf_conf<<<BB * 128, 256, 0, stream>>>(logits, Mst, Tt, out_tags, lens,
                                               out_scores);
    } else {
        crf_decode_fallback<<<BB, 256, 0, stream>>>(logits, trans, lens, out);
    }
}

// Round 16
// 382.846 us; speedup vs baseline: 1.2861x; 1.0094x over previous
//
#include <hip/hip_runtime.h>
#include <math.h>

#define BB 512
#define TT 512
#define OO 64

typedef float f32x4 __attribute__((ext_vector_type(4)));

// =====================================================================
// Kernel 1: transpose trans (16 KB) into ws so conf-pass rows coalesce
// =====================================================================
__global__ void crf_transpose(const float* __restrict__ trans,
                              float* __restrict__ Tt) {
    for (int k = threadIdx.x; k < OO * OO; k += 256)
        Tt[k] = trans[(k & 63) * OO + (k >> 6)];
}

// async 8-row (2 KB) emission stage: 2 x global_load_lds dwordx4
__device__ __forceinline__ void stage8(const float* gsrc_lane, float* ldst) {
    __builtin_amdgcn_global_load_lds(
        (const __attribute__((address_space(1))) unsigned int*)(gsrc_lane),
        (__attribute__((address_space(3))) unsigned int*)(ldst), 16, 0, 0);
    __builtin_amdgcn_global_load_lds(
        (const __attribute__((address_space(1))) unsigned int*)(gsrc_lane + 256),
        (__attribute__((address_space(3))) unsigned int*)(ldst + 256), 16, 0, 0);
}

// =====================================================================
// Kernel 2: single-wave Viterbi scan = R15 (passing) + counted-lgkmcnt
// PIPELINED TREE: DS ops retire in-order per wave and the loop contains
// ONLY our 18 DS ops (write, 16x ds_read_b128, ds_read_b32 x), so
// lgkmcnt(13/9/5/1/0) statically gates {r0-3, r4-7, r8-11, r12-15, x}.
// The max-tree now overlaps the DS pipe instead of waiting for all 16
// reads (R15's lgkmcnt(0) serialized ~200 cyc of pipe time per step).
// All other structure identical to R15: stage8 chunks + vmcnt(9),
// asm M-store, Tc via asm blocks, ballot-backtrack, frozen-past-L.
// =====================================================================
__global__ __launch_bounds__(64, 1) void crf_scan(
    const float* __restrict__ logits,   // [B][T][O]
    const float* __restrict__ trans,    // [O][O]
    const int*   __restrict__ seqlens,  // [B]
    float* __restrict__ out_tags,       // [B][T] (f32)
    float* __restrict__ Mst)            // ws: [B][T][O] f32  (M_0 = 0 row)
{
    const int b = blockIdx.x;
    const int j = threadIdx.x;          // tag 0..63 (also "i" in backtrack)

    __shared__ __align__(16) float st[OO];
    __shared__ __align__(16) float xl[16][OO];   // 2 chunks x 8 rows
    __shared__ float Tt_lds[OO * OO];   // Tt_lds[g*64+i] = T[i][g]
    __shared__ unsigned char tagl[TT];

    const int L = seqlens[b];
    const float* lg = logits + (size_t)b * TT * OO;
    float* Mw = Mst + (size_t)b * TT * OO;

    // build Tt_lds conflict-free (lane j writes column j of each row)
    {
        const f32x4* rowp = (const f32x4*)(trans + j * OO);
        #pragma unroll
        for (int q = 0; q < 16; ++q) {
            f32x4 rv = rowp[q];
            Tt_lds[(4*q+0) * OO + j] = rv[0];
            Tt_lds[(4*q+1) * OO + j] = rv[1];
            Tt_lds[(4*q+2) * OO + j] = rv[2];
            Tt_lds[(4*q+3) * OO + j] = rv[3];
        }
    }

    // Tc[r] = T[r][j], loaded+drained inside single asm blocks
    float Tc[64];
    #define TCBLK(K)                                                      \
    {                                                                     \
        const float* bp = trans + (K) * 16 * OO + j;                      \
        asm volatile(                                                     \
            "global_load_dword %0, %16, off offset:0\n\t"                 \
            "global_load_dword %1, %16, off offset:256\n\t"               \
            "global_load_dword %2, %16, off offset:512\n\t"               \
            "global_load_dword %3, %16, off offset:768\n\t"               \
            "global_load_dword %4, %16, off offset:1024\n\t"              \
            "global_load_dword %5, %16, off offset:1280\n\t"              \
            "global_load_dword %6, %16, off offset:1536\n\t"              \
            "global_load_dword %7, %16, off offset:1792\n\t"              \
            "global_load_dword %8, %16, off offset:2048\n\t"              \
            "global_load_dword %9, %16, off offset:2304\n\t"              \
            "global_load_dword %10, %16, off offset:2560\n\t"             \
            "global_load_dword %11, %16, off offset:2816\n\t"             \
            "global_load_dword %12, %16, off offset:3072\n\t"             \
            "global_load_dword %13, %16, off offset:3328\n\t"             \
            "global_load_dword %14, %16, off offset:3584\n\t"             \
            "global_load_dword %15, %16, off offset:3840\n\t"             \
            "s_waitcnt vmcnt(0)"                                          \
            : "=&v"(Tc[(K)*16+0]),  "=&v"(Tc[(K)*16+1]),                  \
              "=&v"(Tc[(K)*16+2]),  "=&v"(Tc[(K)*16+3]),                  \
              "=&v"(Tc[(K)*16+4]),  "=&v"(Tc[(K)*16+5]),                  \
              "=&v"(Tc[(K)*16+6]),  "=&v"(Tc[(K)*16+7]),                  \
              "=&v"(Tc[(K)*16+8]),  "=&v"(Tc[(K)*16+9]),                  \
              "=&v"(Tc[(K)*16+10]), "=&v"(Tc[(K)*16+11]),                 \
              "=&v"(Tc[(K)*16+12]), "=&v"(Tc[(K)*16+13]),                 \
              "=&v"(Tc[(K)*16+14]), "=&v"(Tc[(K)*16+15])                  \
            : "v"(bp));                                                   \
    }
    TCBLK(0) TCBLK(1) TCBLK(2) TCBLK(3)
    #undef TCBLK

    const unsigned stbase = (unsigned)(size_t)&st[0];
    const unsigned wrAddr = stbase + (unsigned)(j * 4);
    const unsigned xbase4 = (unsigned)(size_t)&xl[0][0] + (unsigned)(j * 4);

    float s = lg[j];                    // state: one value per lane
    Mw[j] = 0.f;                        // M_0 := 0  (s_0 = x_0 + M_0)

    // stage chunks 0,1 (rows 0-15), drain everything
    stage8(lg + j * 4, &xl[0][0]);
    stage8(lg + 8 * OO + j * 4, &xl[8][0]);
    asm volatile("s_waitcnt vmcnt(0)" ::: "memory");
    __builtin_amdgcn_sched_barrier(0);

    f32x4 r0,r1,r2,r3,r4,r5,r6,r7,r8,r9,r10,r11,r12,r13,r14,r15;
    float xreg;

    // publish s, re-broadcast state, read next emission from LDS.
    // Same-wave DS is in-order: write-then-read race-free; retirement
    // order is issue order -> counted lgkmcnt gates exact prefixes.
    #define DSBATCH(XADDR)                                                \
        asm volatile(                                                     \
            "ds_write_b32 %18, %19\n\t"                                   \
            "ds_read_b128 %0, %17 offset:0\n\t"                           \
            "ds_read_b128 %1, %17 offset:16\n\t"                          \
            "ds_read_b128 %2, %17 offset:32\n\t"                          \
            "ds_read_b128 %3, %17 offset:48\n\t"                          \
            "ds_read_b128 %4, %17 offset:64\n\t"                          \
            "ds_read_b128 %5, %17 offset:80\n\t"                          \
            "ds_read_b128 %6, %17 offset:96\n\t"                          \
            "ds_read_b128 %7, %17 offset:112\n\t"                         \
            "ds_read_b128 %8, %17 offset:128\n\t"                         \
            "ds_read_b128 %9, %17 offset:144\n\t"                         \
            "ds_read_b128 %10, %17 offset:160\n\t"                        \
            "ds_read_b128 %11, %17 offset:176\n\t"                        \
            "ds_read_b128 %12, %17 offset:192\n\t"                        \
            "ds_read_b128 %13, %17 offset:208\n\t"                        \
            "ds_read_b128 %14, %17 offset:224\n\t"                        \
            "ds_read_b128 %15, %17 offset:240\n\t"                        \
            "ds_read_b32 %16, %20\n\t"                                    \
            : "=&v"(r0), "=&v"(r1), "=&v"(r2), "=&v"(r3),                 \
              "=&v"(r4), "=&v"(r5), "=&v"(r6), "=&v"(r7),                 \
              "=&v"(r8), "=&v"(r9), "=&v"(r10), "=&v"(r11),               \
              "=&v"(r12), "=&v"(r13), "=&v"(r14), "=&v"(r15), "=&v"(xreg) \
            : "v"(stbase), "v"(wrAddr), "v"(s), "v"(XADDR))

    #define QUAD(q, rr, acc, first)                                       \
    {                                                                     \
        float c0 = rr[0] + Tc[4*(q)+0];                                   \
        float c1 = rr[1] + Tc[4*(q)+1];                                   \
        float c2 = rr[2] + Tc[4*(q)+2];                                   \
        float c3 = rr[3] + Tc[4*(q)+3];                                   \
        float mq = fmaxf(fmaxf(fmaxf(c0, c1), c2), c3);                   \
        acc = first ? mq : fmaxf(acc, mq);                                \
    }

    // prologue: write s_0, read state + x_1 (row 1 -> byte 256)
    DSBATCH(xbase4 + 256u);

    float* mwp = Mw + OO + j;                 // -> M_1 slot
    const float* stgp = lg + 16 * OO + j * 4; // chunk-2 source

    for (int t = 1; t < TT; ++t) {
        // 18 DS ops outstanding (this loop contains no other lgkm ops).
        // Retirement is in issue order -> counted prefix gating:
        asm volatile("s_waitcnt lgkmcnt(13)");  // write + r0..r3 done
        __builtin_amdgcn_sched_barrier(0);
        float m0, m1, m2, m3;
        QUAD(0,  r0,  m0, 1) QUAD(1,  r1,  m1, 1)
        QUAD(2,  r2,  m2, 1) QUAD(3,  r3,  m3, 1)
        asm volatile("s_waitcnt lgkmcnt(9)");   // + r4..r7
        __builtin_amdgcn_sched_barrier(0);
        QUAD(4,  r4,  m0, 0) QUAD(5,  r5,  m1, 0)
        QUAD(6,  r6,  m2, 0) QUAD(7,  r7,  m3, 0)
        asm volatile("s_waitcnt lgkmcnt(5)");   // + r8..r11
        __builtin_amdgcn_sched_barrier(0);
        QUAD(8,  r8,  m0, 0) QUAD(9,  r9,  m1, 0)
        QUAD(10, r10, m2, 0) QUAD(11, r11, m3, 0)
        asm volatile("s_waitcnt lgkmcnt(1)");   // + r12..r15 (x may fly)
        __builtin_amdgcn_sched_barrier(0);
        QUAD(12, r12, m0, 0) QUAD(13, r13, m1, 0)
        QUAD(14, r14, m2, 0) QUAD(15, r15, m3, 0)
        float m = fmaxf(fmaxf(m0, m1), fmaxf(m2, m3));

        if ((t & 7) == 7) {                   // uniform chunk boundary
            int c = (t >> 3) + 2;             // chunk to stage
            if (c < 64) {
                __builtin_amdgcn_sched_barrier(0);
                stage8(stgp, &xl[(c & 1) * 8][0]);
                __builtin_amdgcn_sched_barrier(0);
                stgp += 8 * OO;
            }
        }

        asm volatile("global_store_dword %0, %1, off" :: "v"(mwp), "v"(m));
        mwp += OO;

        asm volatile("s_waitcnt lgkmcnt(0)");   // x-read landed
        __builtin_amdgcn_sched_barrier(0);
        float x = xreg;
        s = (t < L) ? (x + m) : s;            // frozen past L

        if ((t & 7) == 7) {
            // oldest needed stage pair has >=9 newer VMEM ops -> counted
            asm volatile("s_waitcnt vmcnt(9)" ::: "memory");
            __builtin_amdgcn_sched_barrier(0);
        }
        unsigned xaddr = xbase4 + (((unsigned)((t + 1) & 15)) << 8);
        DSBATCH(xaddr);                        // for step t+1 (t=511: unused)
    }
    #undef QUAD
    #undef DSBATCH

    // drain all asm VMEM (backtrack re-reads Mw) + dangling DS batch
    asm volatile("s_waitcnt vmcnt(0) lgkmcnt(0)" ::: "memory");
    __builtin_amdgcn_sched_barrier(0);

    // ---- final argmax over lanes (first-max, exact) ----
    float mm = s;
    #pragma unroll
    for (int d = 1; d < 64; d <<= 1)
        mm = fmaxf(mm, __shfl_xor(mm, d));
    unsigned long long bal = __ballot(s == mm);
    int gcur = (int)__builtin_ctzll(bal);

    // ---- fused exact backtrack: first i with d_i == M_t[gcur] ----
    int t = L - 1;
    if (j == 0) tagl[t] = (unsigned char)gcur;

    float Mt = Mw[t * OO + j];
    float Xp = (t >= 1) ? lg[(t - 1) * OO + j] : 0.f;
    float Mp = (t >= 1) ? Mw[(t - 1) * OO + j] : 0.f;
    float Xq = (t >= 2) ? lg[(t - 2) * OO + j] : 0.f;
    float Mq = (t >= 2) ? Mw[(t - 2) * OO + j] : 0.f;

    while (t >= 1) {
        float target = __uint_as_float(
            (unsigned)__builtin_amdgcn_readlane(__float_as_uint(Mt), gcur));
        float d = (Xp + Mp) + Tt_lds[gcur * OO + j];   // bit-exact recompute
        unsigned long long bl = __ballot(d == target);
        gcur = (int)__builtin_ctzll(bl);               // first-max semantics
        if (j == 0) tagl[t - 1] = (unsigned char)gcur;
        Mt = Mp; Xp = Xq; Mp = Mq;
        if (t >= 3) {
            Xq = lg[(t - 3) * OO + j];
            Mq = Mw[(t - 3) * OO + j];
        }
        --t;
    }
    asm volatile("" ::: "memory");      // lane0 tagl writes before wave reads

    float* ot = out_tags + (size_t)b * TT;
    for (int p = j; p < TT; p += 64)
        ot[p] = (p < L) ? (float)tagl[p] : 0.f;
}

// =====================================================================
// Kernel 3: confidences for decoded path only. One wave per (b,p).
// conf = 1 / sum_i exp(v_i - max v), v_i = (x_p+M_p)[i] + T[i][tag_{p+1}]
// (v_i = s_p[i] for p == L-1). Exact f32. (unchanged, passing)
// =====================================================================
__global__ __launch_bounds__(256) void crf_conf(
    const float* __restrict__ logits,
    const float* __restrict__ Mst,
    const float* __restrict__ Tt,
    const float* __restrict__ out_tags,
    const int*   __restrict__ seqlens,
    float* __restrict__ out_scores)
{
    const int b = blockIdx.x >> 7;
    const int p = ((blockIdx.x & 127) << 2) + (threadIdx.x >> 6);
    const int i = threadIdx.x & 63;
    const int L = seqlens[b];

    if (p >= L) {
        if (i == 0) out_scores[(size_t)b * TT + p] = 0.f;
        return;
    }

    const size_t row = ((size_t)b * TT + p) * OO;
    float v = logits[row + i] + Mst[row + i];
    if (p < L - 1) {
        int g = (int)out_tags[(size_t)b * TT + p + 1];
        v += Tt[g * OO + i];
    }

    float m = v;
    #pragma unroll
    for (int d = 1; d < 64; d <<= 1)
        m = fmaxf(m, __shfl_xor(m, d));
    float e = __expf(v - m);
    #pragma unroll
    for (int d = 1; d < 64; d <<= 1)
        e += __shfl_xor(e, d);

    if (i == 0)
        out_scores[(size_t)b * TT + p] = 1.0f / e;
}

// =====================================================================
// Fallback (proven round-1 kernel): used only if ws too small
// =====================================================================
__global__ __launch_bounds__(256) void crf_decode_fallback(
    const float* __restrict__ logits,
    const float* __restrict__ trans,
    const int*   __restrict__ seqlens,
    float* __restrict__ out)
{
    const int b   = blockIdx.x;
    const int tid = threadIdx.x;
    const int j   = tid >> 2;
    const int c   = tid & 3;

    __shared__ unsigned char bpl[TT][OO];
    __shared__ unsigned char scl[TT][OO];
    __shared__ float st2[2][OO];

    const int L = seqlens[b];
    const float* lg = logits + (size_t)b * TT * OO;

    float trc[16];
    #pragma unroll
    for (int i2 = 0; i2 < 16; ++i2)
        trc[i2] = trans[(c * 16 + i2) * OO + j];

    if (tid < OO) st2[0][tid] = lg[tid];
    __syncthreads();

    int cur = 0;
    for (int t = 1; t < L; ++t) {
        float x = lg[t * OO + j];
        float v[16];
        float m = -1e30f;
        int   idx = 0;
        #pragma unroll
        for (int i2 = 0; i2 < 16; ++i2) {
            float val = st2[cur][c * 16 + i2] + trc[i2];
            v[i2] = val;
            if (val > m) { m = val; idx = c * 16 + i2; }
        }
        #pragma unroll
        for (int d = 1; d <= 2; d <<= 1) {
            float mo = __shfl_xor(m, d);
            int   io = __shfl_xor(idx, d);
            if (mo > m || (mo == m && io < idx)) { m = mo; idx = io; }
        }
        float sden = 0.f;
        #pragma unroll
        for (int i2 = 0; i2 < 16; ++i2)
            sden += __expf(v[i2] - m);
        #pragma unroll
        for (int d = 1; d <= 2; d <<= 1)
            sden += __shfl_xor(sden, d);

        if (c == 0) {
            st2[cur ^ 1][j] = x + m;
            bpl[t][j] = (unsigned char)idx;
            float conf = fminf(1.0f / sden, 1.0f);
            scl[t][j] = (unsigned char)(conf * 255.0f + 0.5f);
        }
        cur ^= 1;
        __syncthreads();
    }

    if (tid == 0) {
        float m = -1e30f; int idx = 0;
        for (int jj = 0; jj < OO; ++jj) {
            float vv = st2[cur][jj];
            if (vv > m) { m = vv; idx = jj; }
        }
        float sden = 0.f;
        for (int jj = 0; jj < OO; ++jj)
            sden += __expf(st2[cur][jj] - m);

        float* out_tags   = out + (size_t)b * TT;
        float* out_scores = out + (size_t)BB * TT + (size_t)b * TT;
        out_tags[L - 1]   = (float)idx;
        out_scores[L - 1] = 1.0f / sden;

        int tag = idx;
        for (int t = L - 1; t >= 1; --t) {
            int ntag  = bpl[t][tag];
            float sc  = (float)scl[t][tag] * (1.0f / 255.0f);
            out_tags[t - 1]   = (float)ntag;
            out_scores[t - 1] = sc;
            tag = ntag;
        }
    }

    float* out_tags   = out + (size_t)b * TT;
    float* out_scores = out + (size_t)BB * TT + (size_t)b * TT;
    for (int p = L + tid; p < TT; p += 256) {
        out_tags[p]   = 0.f;
        out_scores[p] = 0.f;
    }
}

extern "C" void kernel_launch(void* const* d_in, const int* in_sizes, int n_in,
                              void* d_out, int out_size, void* d_ws, size_t ws_size,
                              hipStream_t stream) {
    const float* logits = (const float*)d_in[0];
    const float* trans  = (const float*)d_in[1];
    const int*   lens   = (const int*)d_in[2];
    float* out = (float*)d_out;

    const size_t m_bytes  = (size_t)BB * TT * OO * sizeof(float); // 64 MB
    const size_t tt_bytes = (size_t)OO * OO * sizeof(float);      // 16 KB
    if (ws_size >= m_bytes + tt_bytes) {
        float* Mst = (float*)d_ws;
        float* Tt  = (float*)((char*)d_ws + m_bytes);
        float* out_tags   = out;
        float* out_scores = out + (size_t)BB * TT;

        crf_transpose<<<1, 256, 0, stream>>>(trans, Tt);
        crf_scan<<<BB, 64, 0, stream>>>(logits, trans, lens, out_tags, Mst);
        crf_conf<<<BB * 128, 256, 0, stream>>>(logits, Mst, Tt, out_tags, lens,
                                               out_scores);
    } else {
        crf_decode_fallback<<<BB, 256, 0, stream>>>(logits, trans, lens, out);
    }
}